// Round 1
// 332.596 us; speedup vs baseline: 1.0474x; 1.0474x over previous
//
#include <hip/hip_runtime.h>

#define IMG 28
#define NPIX (IMG * IMG)          // 784
#define NVEC (NPIX / 4)           // 196 float4 per image
#define CENTER 14

typedef float f4 __attribute__((ext_vector_type(4)));

// out = x everywhere except the annulus {(t-1)^2 < d2 <= t^2} (t=0: center
// pixel only), where out = x + conv3x3(x) + b.  Cross-correlation, SAME pad.
//
// Structure: 1 wave = 1 image, 4 images / 256-thread block.
// KEY CHANGE vs previous version: no __syncthreads(). Each wave stages its
// image into its OWN LDS segment and only ever reads that segment back —
// there is zero cross-wave LDS sharing, so intra-wave lgkmcnt ordering
// (compiler-inserted) is sufficient. This decouples the four waves' memory
// latency (previously max-of-4 per block behind the barrier).
__global__ __launch_bounds__(256) void SuperResolution_89876485636254_kernel(
    const float* __restrict__ x,
    const int*   __restrict__ t,
    const float* __restrict__ Wk,
    const float* __restrict__ bias,
    float*       __restrict__ out)
{
    __shared__ float s[4][NPIX];

    const int wave = threadIdx.x >> 6;
    const int lane = threadIdx.x & 63;
    const int img  = blockIdx.x * 4 + wave;

    const f4* __restrict__ xin4 = (const f4*)(x + (size_t)img * NPIX);
    f4*       __restrict__ out4 = (f4*)(out + (size_t)img * NPIX);
    f4*       s4 = (f4*)s[wave];

    // wave-uniform metadata first (tiny, L2-resident)
    const int rt = t[img];

    // issue all global loads up front (independent; nontemporal: x is
    // touch-once — conv neighbors are served from LDS, never from global)
    f4 v[4];
    v[0] = __builtin_nontemporal_load(xin4 + lane);
    v[1] = __builtin_nontemporal_load(xin4 + lane + 64);
    v[2] = __builtin_nontemporal_load(xin4 + lane + 128);
    if (lane < 4) v[3] = __builtin_nontemporal_load(xin4 + lane + 192);

    const int r2  = rt * rt;
    const int ir2 = (rt >= 1) ? (rt - 1) * (rt - 1) : -1;  // inner radius^2
    const float bb = bias[0];
    float w[9];
    #pragma unroll
    for (int i = 0; i < 9; ++i) w[i] = Wk[i];

    // stage into this wave's private LDS segment (no barrier needed)
    s4[lane]       = v[0];
    s4[lane + 64]  = v[1];
    s4[lane + 128] = v[2];
    if (lane < 4) s4[lane + 192] = v[3];

    const float* __restrict__ simg = s[wave];

    #pragma unroll
    for (int kk = 0; kk < 4; ++kk) {
        if (kk < 3 || lane < 4) {
            const int k = lane + kk * 64;
            f4 r = v[kk];
            const int p   = 4 * k;
            const int i   = k / 7;           // = p / IMG  (28 == 4*7)
            const int j0  = p - i * IMG;
            const int di  = i - CENTER;
            const int di2 = di * di;
            // row-band early-out: di2 > r2  =>  d2 > r2 for all 4 pixels
            if (di2 <= r2) {
                #pragma unroll
                for (int e = 0; e < 4; ++e) {
                    const int j  = j0 + e;
                    const int dj = j - CENTER;
                    const int d2 = di2 + dj * dj;
                    if (d2 <= r2 && d2 > ir2) {
                        float acc = bb;
                        #pragma unroll
                        for (int a = 0; a < 3; ++a) {
                            const int ii = i + a - 1;
                            if (ii >= 0 && ii < IMG) {
                                #pragma unroll
                                for (int c = 0; c < 3; ++c) {
                                    const int jj = j + c - 1;
                                    if (jj >= 0 && jj < IMG)
                                        acc += w[a * 3 + c] * simg[ii * IMG + jj];
                                }
                            }
                        }
                        r[e] += acc;
                    }
                }
            }
            __builtin_nontemporal_store(r, out4 + k);  // out is touch-once
        }
    }
}

extern "C" void kernel_launch(void* const* d_in, const int* in_sizes, int n_in,
                              void* d_out, int out_size, void* d_ws, size_t ws_size,
                              hipStream_t stream) {
    const float* x    = (const float*)d_in[0];
    const int*   t    = (const int*)d_in[1];
    const float* Wk   = (const float*)d_in[2];
    const float* bias = (const float*)d_in[3];
    float*       out  = (float*)d_out;

    const int B = in_sizes[0] / NPIX;        // 65536
    const int blocks = B / 4;                // 4 images per 256-thread block

    SuperResolution_89876485636254_kernel<<<blocks, 256, 0, stream>>>(
        x, t, Wk, bias, out);
}

// Round 4
// 328.467 us; speedup vs baseline: 1.0606x; 1.0126x over previous
//
#include <hip/hip_runtime.h>

#define IMG 28
#define NPIX (IMG * IMG)          // 784
#define CENTER 14
#define SROW 32                   // LDS row pitch (floats)
#define SPAD 4                    // front pad so (row0,col-1) reads stay in-bounds
#define SFLOATS (30 * SROW + SPAD) // 964 floats = 3856 B per wave

typedef float f4 __attribute__((ext_vector_type(4)));

// out = x everywhere except the annulus {(t-1)^2 < d2 <= t^2} (t=0: center
// pixel only), where out = x + conv3x3(x) + b.  Cross-correlation, SAME pad.
//
// Structure: 1 wave = 1 image, 4 images / 256-thread block, no barriers
// (each wave only reads the LDS segment it wrote; intra-wave lgkmcnt orders).
//
//  - __launch_bounds__(256, 4): modest occupancy hint (4 blocks/CU, 128-VGPR
//    budget). De-risked from (256,8) after two container failures -- the
//    hard 64-VGPR max-occupancy clamp was the only new compile-level
//    constraint vs the round-1 source that ran clean.
//  - Zero-haloed LDS image (30 x 32-pitch + 4-float front pad): conv is
//    9 UNCONDITIONAL ds_reads at fixed offsets -- no ii/jj bounds cascade.
//    Zero-product taps are exact identities -> bit-identical results.
__global__ __launch_bounds__(256, 4) void SuperResolution_89876485636254_kernel(
    const float* __restrict__ x,
    const int*   __restrict__ t,
    const float* __restrict__ Wk,
    const float* __restrict__ bias,
    float*       __restrict__ out)
{
    __shared__ float s2[4][SFLOATS];

    const int wave = threadIdx.x >> 6;
    const int lane = threadIdx.x & 63;
    const int img  = blockIdx.x * 4 + wave;

    const f4* __restrict__ xin4 = (const f4*)(x + (size_t)img * NPIX);
    f4*       __restrict__ out4 = (f4*)(out + (size_t)img * NPIX);

    // wave-uniform metadata first
    const int rt = t[img];

    // issue all global loads up front (touch-once stream)
    f4 v[4];
    v[0] = __builtin_nontemporal_load(xin4 + lane);
    v[1] = __builtin_nontemporal_load(xin4 + lane + 64);
    v[2] = __builtin_nontemporal_load(xin4 + lane + 128);
    if (lane < 4) v[3] = __builtin_nontemporal_load(xin4 + lane + 192);

    const int r2  = rt * rt;
    const int ir2 = (rt >= 1) ? (rt - 1) * (rt - 1) : -1;  // inner radius^2
    const float bb = bias[0];
    float w[9];
    #pragma unroll
    for (int i = 0; i < 9; ++i) w[i] = Wk[i];

    f4* sw4 = (f4*)s2[wave];

    // zero the halo: front pad (1 f4) + row0 (8) + row29 (8) + cols28..31 of
    // rows 1..28 (28) = 45 f4 writes, one per lane 0..44
    if (lane < 45) {
        const int zi = (lane < 9)  ? lane
                     : (lane < 17) ? 224 + lane          // 233 + (lane-9)
                     :               8 * (lane - 15);    // 16,24,...,232
        f4 z = {0.f, 0.f, 0.f, 0.f};
        sw4[zi] = z;
    }

    // stage image at (row i+1, col j0) of the haloed layout
    #pragma unroll
    for (int kk = 0; kk < 4; ++kk) {
        if (kk < 3 || lane < 4) {
            const int k = lane + kk * 64;
            const int i = k / 7;                  // row (7 f4 per 28-px row)
            sw4[1 + 8 * (i + 1) + (k - 7 * i)] = v[kk];
        }
    }

    const float* __restrict__ simg = s2[wave];

    #pragma unroll
    for (int kk = 0; kk < 4; ++kk) {
        if (kk < 3 || lane < 4) {
            const int k = lane + kk * 64;
            f4 r = v[kk];
            const int i   = k / 7;
            const int j0  = 4 * (k - 7 * i);
            const int di  = i - CENTER;
            const int di2 = di * di;
            // row-band early-out: di2 > r2 => whole f4 is a pure copy
            if (di2 <= r2) {
                const float* base0 = simg + SPAD + (i + 1) * SROW + j0;
                #pragma unroll
                for (int e = 0; e < 4; ++e) {
                    const int j  = j0 + e;
                    const int dj = j - CENTER;
                    const int d2 = di2 + dj * dj;
                    if (d2 <= r2 && d2 > ir2) {
                        const float* b = base0 + e;
                        float acc = bb;
                        acc += w[0] * b[-SROW - 1];
                        acc += w[1] * b[-SROW];
                        acc += w[2] * b[-SROW + 1];
                        acc += w[3] * b[-1];
                        acc += w[4] * b[0];
                        acc += w[5] * b[1];
                        acc += w[6] * b[SROW - 1];
                        acc += w[7] * b[SROW];
                        acc += w[8] * b[SROW + 1];
                        r[e] += acc;
                    }
                }
            }
            __builtin_nontemporal_store(r, out4 + k);  // out is touch-once
        }
    }
}

extern "C" void kernel_launch(void* const* d_in, const int* in_sizes, int n_in,
                              void* d_out, int out_size, void* d_ws, size_t ws_size,
                              hipStream_t stream) {
    const float* x    = (const float*)d_in[0];
    const int*   t    = (const int*)d_in[1];
    const float* Wk   = (const float*)d_in[2];
    const float* bias = (const float*)d_in[3];
    float*       out  = (float*)d_out;

    const int B = in_sizes[0] / NPIX;        // 65536
    const int blocks = B / 4;                // 4 images per 256-thread block

    SuperResolution_89876485636254_kernel<<<blocks, 256, 0, stream>>>(
        x, t, Wk, bias, out);
}